// Round 9
// baseline (136.632 us; speedup 1.0000x reference)
//
#include <hip/hip_runtime.h>
#include <hip/hip_bf16.h>
#include <math.h>

typedef short bf16x8 __attribute__((ext_vector_type(8)));      // 8 bf16 = 4 VGPRs
typedef short short4v __attribute__((ext_vector_type(4)));     // 4 bf16 = 2 VGPRs
typedef float f32x4 __attribute__((ext_vector_type(4)));
typedef float float4v __attribute__((ext_vector_type(4)));
typedef unsigned short ushort4v __attribute__((ext_vector_type(4))); // 8 bytes

// cheap elu: exp(x)-1 via hardware v_exp_f32 (error ~1e-7 abs, threshold 3.4e-4)
static __device__ __forceinline__ float eluf(float x) {
  float e = __expf(x) - 1.0f;
  return x > 0.f ? x : e;
}
static __device__ __forceinline__ unsigned short f2bf(float f) {
  __hip_bfloat16 h = __float2bfloat16(f);
  return *reinterpret_cast<unsigned short*>(&h);
}
static __device__ __forceinline__ unsigned short f2bf_rne(float f) {
  union { float f; unsigned u; } v; v.f = f;
  unsigned r = v.u + 0x7FFFu + ((v.u >> 16) & 1u);
  return (unsigned short)(r >> 16);
}
// keep a loaded fragment materialized HERE (prevents load sinking / re-load)
#define PIN(x) asm volatile("" :: "v"(x))

// ---------------- prologue 1: h = elu(A_flat @ W1^T), h[256] ----------------
__global__ void k_hidden(const float* __restrict__ A, const float* __restrict__ W1,
                         float* __restrict__ hout) {
  int j = blockIdx.x, t = threadIdx.x;
  const float* row = W1 + (size_t)j * 4096;
  float s = 0.f;
  for (int i = t; i < 4096; i += 256) s += A[i] * row[i];
  __shared__ float red[256];
  red[t] = s; __syncthreads();
  for (int off = 128; off > 0; off >>= 1) {
    if (t < off) red[t] += red[t + off];
    __syncthreads();
  }
  if (t == 0) {
    float x = red[0];
    hout[j] = x > 0.f ? x : expm1f(x);   // prologue: keep precise
  }
}

// -------- prologue 2 (fused): blocks 0-63 = D rownorm; blocks 64+ = T-transpose
__global__ void k_pre2(const float* __restrict__ hbuf, const float* __restrict__ W2,
                       unsigned short* __restrict__ Dout,
                       const float* __restrict__ T1, const float* __restrict__ T2,
                       unsigned short* __restrict__ T1T, unsigned short* __restrict__ T2T) {
  int t = threadIdx.x;
  if (blockIdx.x < 64) {
    int x = blockIdx.x;
    int lane = t & 63, w = t >> 6;
    __shared__ float hs[256];
    __shared__ float ad[64];
    hs[t] = hbuf[t];
    __syncthreads();
    for (int ei = 0; ei < 16; ++ei) {
      int e = w * 16 + ei;
      const float* row = W2 + (size_t)(x * 64 + e) * 256;
      float p = 0.f;
      for (int q = 0; q < 4; ++q) p += row[q * 64 + lane] * hs[q * 64 + lane];
      for (int off = 32; off > 0; off >>= 1) p += __shfl_down(p, off);
      if (lane == 0) ad[e] = fmaxf(p, 0.f);
    }
    __syncthreads();
    if (t < 64) {
      float v = ad[t];
      float rs = v;
      for (int off = 1; off < 64; off <<= 1) rs += __shfl_xor(rs, off);
      Dout[x * 64 + t] = f2bf_rne(v / fmaxf(rs, 1e-6f));
    }
  } else {
    int idx = (blockIdx.x - 64) * 256 + t;      // 0 .. 163839
    const float* src = (idx < 81920) ? T1 : T2;
    unsigned short* dst = (idx < 81920) ? T1T : T2T;
    int o = (idx < 81920) ? idx : idx - 81920;
    int g = o >> 14;
    int r = o & 16383;
    int h = r >> 7;      // out row = n index
    int f = r & 127;     // out col = k index
    dst[o] = f2bf_rne(src[g * 16384 + f * 128 + h]);
  }
}

// ---------------- main: per (g,b): out = elu(D @ elu(mu@T1) @ T2) ----------
// Block = NB=2 consecutive b for one g (grid 2560 -> 10 slots/CU); 4 waves;
// wave w owns n-cols [32w,32w+32). T1/D/T2 fragments loaded ONCE pre-loop and
// PINNED in registers (asm materialization) so the compiler cannot sink the
// loads back into the GEMMs (the R3/R7/R8 failure mode: VGPR=48 + serialized
// L2 round-trips). GEMM1->GEMM2 handoff in registers (16x16x16 B-frag
// identity). LDS = 2x16KB mu (bf16, swz) double-buffer; h2 aliases bcur.
// mu_{it+1} prefetched to regs at iter top (sched_barrier(0) pins issue),
// LDS-written after B1 -> HBM latency hides under GEMM1+cvt+GEMM2.
// (256,2): up to 256 VGPR, no spill; peak live ~176.
__launch_bounds__(256, 2)
__global__ void k_main(const float* __restrict__ mu,
                       const unsigned short* __restrict__ Dm,
                       const unsigned short* __restrict__ T1T,
                       const unsigned short* __restrict__ T2T,
                       float* __restrict__ out) {
  __shared__ __align__(16) char smem[32768];

  const int g = blockIdx.y, b0 = blockIdx.x * 2;
  const int t = threadIdx.x;
  const int lane = t & 63, w = t >> 6;
  const int l15 = lane & 15, lk = lane >> 4;
  const int nb = w * 32;

  // ---- load + PIN persistent fragments (96 VGPR, L2-hot, once per block) ----
  const unsigned short* t1g = T1T + g * 16384;
  const unsigned short* t2g = T2T + g * 16384;
  bf16x8 tb0[4], tb1[4], t2b0[4], t2b1[4];
  #pragma unroll
  for (int kc = 0; kc < 4; ++kc) {
    int k0 = kc * 32 + lk * 8;
    tb0[kc]  = *(const bf16x8*)(const void*)(t1g + (nb + l15) * 128 + k0);
    tb1[kc]  = *(const bf16x8*)(const void*)(t1g + (nb + 16 + l15) * 128 + k0);
    t2b0[kc] = *(const bf16x8*)(const void*)(t2g + (nb + l15) * 128 + k0);
    t2b1[kc] = *(const bf16x8*)(const void*)(t2g + (nb + 16 + l15) * 128 + k0);
  }
  short4v aDf[4][4];
  #pragma unroll
  for (int mp = 0; mp < 4; ++mp)
    #pragma unroll
    for (int kc = 0; kc < 4; ++kc)
      aDf[mp][kc] = *(const short4v*)(const void*)(Dm + (mp * 16 + l15) * 64 + kc * 16 + lk * 4);
  #pragma unroll
  for (int kc = 0; kc < 4; ++kc) { PIN(tb0[kc]); PIN(tb1[kc]); PIN(t2b0[kc]); PIN(t2b1[kc]); }
  #pragma unroll
  for (int mp = 0; mp < 4; ++mp)
    #pragma unroll
    for (int kc = 0; kc < 4; ++kc) PIN(aDf[mp][kc]);

  // ---- prologue: stage mu for it=0 into buf0 (write-side cvt, swizzled) ----
  {
    const float4v* src = (const float4v*)(mu + (size_t)(g * 1024 + b0) * 8192);
    #pragma unroll
    for (int k = 0; k < 8; ++k) {
      int q = t + k * 256;
      float4v v = src[q];
      int row = q >> 5, col4 = (q & 31) * 4;
      ushort4v u;
      u[0] = f2bf(v[0]); u[1] = f2bf(v[1]); u[2] = f2bf(v[2]); u[3] = f2bf(v[3]);
      *(ushort4v*)(smem + ((row * 256 + col4 * 2) ^ ((row & 7) << 4))) = u;
    }
  }
  __syncthreads();

  #pragma unroll 1
  for (int it = 0; it < 2; ++it) {
    char* bcur = smem + ((it & 1) << 14);
    char* bnxt = smem + (((it + 1) & 1) << 14);
    const bool pre = (it < 1);

    // issue next-iter mu loads; pin issue point so hipcc can't sink them
    float4v vn[8];
    if (pre) {
      const float4v* srcn = (const float4v*)(mu + (size_t)(g * 1024 + b0 + it + 1) * 8192);
      #pragma unroll
      for (int k = 0; k < 8; ++k) vn[k] = srcn[t + k * 256];
      __builtin_amdgcn_sched_barrier(0);
    }

    // ---- GEMM1: h1 = mu @ T1 (M=e 64, N=h 128, K=f 128) ----
    f32x4 acc[4][2];
    #pragma unroll
    for (int m = 0; m < 4; ++m) { acc[m][0] = (f32x4){0,0,0,0}; acc[m][1] = (f32x4){0,0,0,0}; }
    #pragma unroll
    for (int kc = 0; kc < 4; ++kc) {
      int k0 = kc * 32 + lk * 8;
      #pragma unroll
      for (int m = 0; m < 4; ++m) {
        int row = m * 16 + l15;
        bf16x8 a = *(const bf16x8*)(bcur + ((row * 256 + k0 * 2) ^ ((row & 7) << 4)));
        acc[m][0] = __builtin_amdgcn_mfma_f32_16x16x32_bf16(a, tb0[kc], acc[m][0], 0, 0, 0);
        acc[m][1] = __builtin_amdgcn_mfma_f32_16x16x32_bf16(a, tb1[kc], acc[m][1], 0, 0, 0);
      }
    }

    // ---- elu + cvt -> bf16x4 B-frags for GEMM2 (registers only) ----
    short4v bfr[4][2];
    #pragma unroll
    for (int m = 0; m < 4; ++m)
      #pragma unroll
      for (int n = 0; n < 2; ++n) {
        short4v s;
        s[0] = (short)f2bf(eluf(acc[m][n][0]));
        s[1] = (short)f2bf(eluf(acc[m][n][1]));
        s[2] = (short)f2bf(eluf(acc[m][n][2]));
        s[3] = (short)f2bf(eluf(acc[m][n][3]));
        bfr[m][n] = s;
      }

    // ---- GEMM2: h2 = D @ h1 (M=x 64, N=h 128, K=e 64) via 16x16x16 ----
    f32x4 acc2[4][2];
    #pragma unroll
    for (int mp = 0; mp < 4; ++mp) { acc2[mp][0] = (f32x4){0,0,0,0}; acc2[mp][1] = (f32x4){0,0,0,0}; }
    #pragma unroll
    for (int kc = 0; kc < 4; ++kc)
      #pragma unroll
      for (int mp = 0; mp < 4; ++mp) {
        acc2[mp][0] = __builtin_amdgcn_mfma_f32_16x16x16bf16_1k(aDf[mp][kc], bfr[kc][0], acc2[mp][0], 0, 0, 0);
        acc2[mp][1] = __builtin_amdgcn_mfma_f32_16x16x16bf16_1k(aDf[mp][kc], bfr[kc][1], acc2[mp][1], 0, 0, 0);
      }

    __syncthreads();   // B1: all waves done with bcur (mu) -> reusable as h2

    // ---- h2[x][h] scatter into bcur (b16 writes, swz on x) ----
    #pragma unroll
    for (int mp = 0; mp < 4; ++mp)
      #pragma unroll
      for (int n = 0; n < 2; ++n) {
        int hc = nb + n * 16 + l15;
        #pragma unroll
        for (int r = 0; r < 4; ++r) {
          int x = mp * 16 + lk * 4 + r;
          *(unsigned short*)(bcur + ((x * 256 + hc * 2) ^ ((x & 7) << 4))) = f2bf(acc2[mp][n][r]);
        }
      }
    // stage mu_{it+1} -> bnxt (vn waitcnt here; latency covered by G1+cvt+G2)
    if (pre) {
      #pragma unroll
      for (int k = 0; k < 8; ++k) {
        int q = t + k * 256;
        int row = q >> 5, col4 = (q & 31) * 4;
        ushort4v u;
        u[0] = f2bf(vn[k][0]); u[1] = f2bf(vn[k][1]);
        u[2] = f2bf(vn[k][2]); u[3] = f2bf(vn[k][3]);
        *(ushort4v*)(bnxt + ((row * 256 + col4 * 2) ^ ((row & 7) << 4))) = u;
      }
    }
    __syncthreads();   // B2: h2 + mu_next visible

    // ---- GEMM3: out = elu(h2 @ T2) (M=x 64, N=f 128, K=h 128) ----
    f32x4 acc3[4][2];
    #pragma unroll
    for (int m = 0; m < 4; ++m) { acc3[m][0] = (f32x4){0,0,0,0}; acc3[m][1] = (f32x4){0,0,0,0}; }
    #pragma unroll
    for (int kc = 0; kc < 4; ++kc) {
      int k0 = kc * 32 + lk * 8;
      #pragma unroll
      for (int m = 0; m < 4; ++m) {
        int row = m * 16 + l15;
        bf16x8 a = *(const bf16x8*)(bcur + ((row * 256 + k0 * 2) ^ ((row & 7) << 4)));
        acc3[m][0] = __builtin_amdgcn_mfma_f32_16x16x32_bf16(a, t2b0[kc], acc3[m][0], 0, 0, 0);
        acc3[m][1] = __builtin_amdgcn_mfma_f32_16x16x32_bf16(a, t2b1[kc], acc3[m][1], 0, 0, 0);
      }
    }
    float* ob = out + (size_t)(g * 1024 + b0 + it) * 8192;
    #pragma unroll
    for (int m = 0; m < 4; ++m)
      #pragma unroll
      for (int n = 0; n < 2; ++n) {
        int f = nb + n * 16 + l15;
        #pragma unroll
        for (int r = 0; r < 4; ++r) {
          int e = m * 16 + lk * 4 + r;
          ob[e * 128 + f] = eluf(acc3[m][n][r]);
        }
      }
  }
}

extern "C" void kernel_launch(void* const* d_in, const int* in_sizes, int n_in,
                              void* d_out, int out_size, void* d_ws, size_t ws_size,
                              hipStream_t stream) {
  const float* mu = (const float*)d_in[0];
  const float* A  = (const float*)d_in[1];
  const float* W1 = (const float*)d_in[2];
  const float* W2 = (const float*)d_in[3];
  const float* T1 = (const float*)d_in[4];
  const float* T2 = (const float*)d_in[5];
  float* out = (float*)d_out;

  char* ws = (char*)d_ws;
  float* hbuf          = (float*)ws;                     // 1 KB
  unsigned short* Dm   = (unsigned short*)(ws + 1024);   // 8 KB
  unsigned short* T1T  = (unsigned short*)(ws + 9216);   // 160 KB
  unsigned short* T2T  = (unsigned short*)(ws + 173056); // 160 KB

  hipLaunchKernelGGL(k_hidden, dim3(256), dim3(256), 0, stream, A, W1, hbuf);
  hipLaunchKernelGGL(k_pre2,   dim3(704), dim3(256), 0, stream, hbuf, W2, Dm, T1, T2, T1T, T2T);
  hipLaunchKernelGGL(k_main,   dim3(512, 5), dim3(256), 0, stream, mu, Dm, T1T, T2T, out);
}